// Round 1
// baseline (1797.000 us; speedup 1.0000x reference)
//
#include <hip/hip_runtime.h>
#include <hip/hip_bf16.h>

#define Bb 4
#define Ss 2048
#define Dm 1024
#define Hh 16
#define DK 64
#define Mm (Bb*Ss)   // 8192

typedef __attribute__((ext_vector_type(8))) short short8;
typedef __attribute__((ext_vector_type(4))) float floatx4;

static __device__ __forceinline__ unsigned short f2bf(float f) {
  union { float f; unsigned u; } x; x.f = f;
  unsigned r = x.u + 0x7fffu + ((x.u >> 16) & 1u);
  return (unsigned short)(r >> 16);
}
static __device__ __forceinline__ float bf2f(unsigned short u) {
  union { unsigned u; float f; } x; x.u = ((unsigned)u) << 16; return x.f;
}

// ---------------------------------------------------------------------------
// Projection GEMM: out = A @ W^T + b, A fp32 [8192,1024], W fp32 [1024,1024]
// z=0 -> Qh [B,H,S,64] bf16 ; z=1 -> Kh [B,H,S,64] ; z=2 -> Vt [B,H,64,S]
// ---------------------------------------------------------------------------
#define BM 128
#define BN 128
#define BK 64
#define LDT 72   // BK + 8 bf16 pad (keeps 16B alignment, breaks bank stride)

__global__ __launch_bounds__(256, 2) void proj_gemm(
    const float* __restrict__ Aq, const float* __restrict__ Ak, const float* __restrict__ Av,
    const float* __restrict__ Wq, const float* __restrict__ Wk, const float* __restrict__ Wv,
    const float* __restrict__ bq, const float* __restrict__ bk, const float* __restrict__ bv,
    unsigned short* __restrict__ Qh, unsigned short* __restrict__ Kh, unsigned short* __restrict__ Vt)
{
  const int z = blockIdx.z;
  const float* A    = (z == 0) ? Aq : (z == 1) ? Ak : Av;
  const float* W    = (z == 0) ? Wq : (z == 1) ? Wk : Wv;
  const float* bias = (z == 0) ? bq : (z == 1) ? bk : bv;
  unsigned short* out = (z == 0) ? Qh : (z == 1) ? Kh : Vt;

  __shared__ unsigned short As[BM][LDT];
  __shared__ unsigned short Ws[BN][LDT];

  const int t = threadIdx.x;
  const int lane = t & 63;
  const int w = t >> 6;            // 4 waves
  const int wm = w & 1, wn = w >> 1;
  const int quad = lane >> 4, l16 = lane & 15;
  const int mtile = blockIdx.x, ntile = blockIdx.y;

  floatx4 acc[4][4] = {};

  for (int kt = 0; kt < Dm / BK; ++kt) {
    __syncthreads();
    #pragma unroll
    for (int j = 0; j < 8; ++j) {
      int c = j * 256 + t;               // 0..2047 chunks of float4
      int row = c >> 4, col4 = c & 15;
      float4 va = *(const float4*)(A + (size_t)(mtile * BM + row) * Dm + kt * BK + col4 * 4);
      unsigned short* pa = &As[row][col4 * 4];
      pa[0] = f2bf(va.x); pa[1] = f2bf(va.y); pa[2] = f2bf(va.z); pa[3] = f2bf(va.w);
      float4 vw = *(const float4*)(W + (size_t)(ntile * BN + row) * Dm + kt * BK + col4 * 4);
      unsigned short* pw = &Ws[row][col4 * 4];
      pw[0] = f2bf(vw.x); pw[1] = f2bf(vw.y); pw[2] = f2bf(vw.z); pw[3] = f2bf(vw.w);
    }
    __syncthreads();
    #pragma unroll
    for (int kk = 0; kk < 2; ++kk) {
      short8 af[4], bf[4];
      #pragma unroll
      for (int i = 0; i < 4; ++i) {
        af[i] = *(const short8*)&As[wm * 64 + i * 16 + l16][kk * 32 + quad * 8];
        bf[i] = *(const short8*)&Ws[wn * 64 + i * 16 + l16][kk * 32 + quad * 8];
      }
      #pragma unroll
      for (int i = 0; i < 4; ++i)
        #pragma unroll
        for (int jn = 0; jn < 4; ++jn)
          acc[i][jn] = __builtin_amdgcn_mfma_f32_16x16x32_bf16(af[i], bf[jn], acc[i][jn], 0, 0, 0);
    }
  }

  // epilogue: bias + bf16 store to head-major layouts
  #pragma unroll
  for (int i = 0; i < 4; ++i) {
    int m0 = mtile * BM + wm * 64 + i * 16 + quad * 4;
    #pragma unroll
    for (int jn = 0; jn < 4; ++jn) {
      int n = ntile * BN + wn * 64 + jn * 16 + l16;
      float bv_ = bias[n];
      int h = n >> 6, d = n & 63;
      if (z < 2) {
        #pragma unroll
        for (int r = 0; r < 4; ++r) {
          int m = m0 + r;
          int bbi = m >> 11, s = m & 2047;
          out[(((size_t)(bbi * Hh + h)) * Ss + s) * DK + d] = f2bf(acc[i][jn][r] + bv_);
        }
      } else {
        int bbi = m0 >> 11, s0 = m0 & 2047;
        unsigned short* p = &out[(((size_t)(bbi * Hh + h)) * DK + d) * Ss + s0];
        // 4 consecutive s values -> one 8B store
        unsigned short v0 = f2bf(acc[i][jn][0] + bv_);
        unsigned short v1 = f2bf(acc[i][jn][1] + bv_);
        unsigned short v2 = f2bf(acc[i][jn][2] + bv_);
        unsigned short v3 = f2bf(acc[i][jn][3] + bv_);
        unsigned long long pk = (unsigned long long)v0 | ((unsigned long long)v1 << 16)
                              | ((unsigned long long)v2 << 32) | ((unsigned long long)v3 << 48);
        *(unsigned long long*)p = pk;
      }
    }
  }
}

// ---------------------------------------------------------------------------
// Fused attention: per (b*h, 32-row q tile): QK^T -> exp -> LDS P (bf16,
// unnormalized), row sums -> inv_l; write attn = P*inv_l (fp32, NT stores);
// O = (P @ V) * inv_l -> AO bf16 [B,S,1024]
// ---------------------------------------------------------------------------
#define PLD 2056   // 2048 + 8 bf16 pad (16B-aligned row stride)

__global__ __launch_bounds__(512, 2) void attn_kernel(
    const unsigned short* __restrict__ Qh, const unsigned short* __restrict__ Kh,
    const unsigned short* __restrict__ Vt, unsigned short* __restrict__ AO,
    float* __restrict__ attn)
{
  extern __shared__ char smem[];
  unsigned short* P = (unsigned short*)smem;                 // [32][PLD]
  float* sums = (float*)(smem + 32 * PLD * 2);               // [4][32]
  float* invl = sums + 4 * 32;                               // [32]

  const int t = threadIdx.x;
  const int lane = t & 63, w = t >> 6;       // 8 waves
  const int quad = lane >> 4, l16 = lane & 15;
  const int qt = blockIdx.x, bh = blockIdx.y;
  const int qb = w & 1, kb = w >> 1;         // phase1: kb = k-block; phase2: db

  const size_t hb = (size_t)bh * Ss * DK;

  // Q A-fragments (persist in registers for phase 1)
  short8 aq0, aq1;
  {
    const unsigned short* qp = Qh + hb + (size_t)(qt * 32 + qb * 16 + l16) * DK + quad * 8;
    aq0 = *(const short8*)(qp);
    aq1 = *(const short8*)(qp + 32);
  }

  float sacc[4] = {0.f, 0.f, 0.f, 0.f};

  // ---- phase 1: scores + exp into LDS, running row sums ----
  for (int c = 0; c < 32; ++c) {
    int kbase = c * 64 + kb * 16;
    const unsigned short* kp = Kh + hb + (size_t)(kbase + l16) * DK + quad * 8;
    short8 b0 = *(const short8*)(kp);
    short8 b1 = *(const short8*)(kp + 32);
    floatx4 s = {0.f, 0.f, 0.f, 0.f};
    s = __builtin_amdgcn_mfma_f32_16x16x32_bf16(aq0, b0, s, 0, 0, 0);
    s = __builtin_amdgcn_mfma_f32_16x16x32_bf16(aq1, b1, s, 0, 0, 0);
    int col = kbase + l16;
    #pragma unroll
    for (int r = 0; r < 4; ++r) {
      float e = __expf(s[r] * 0.125f);
      sacc[r] += e;
      P[(qb * 16 + quad * 4 + r) * PLD + col] = f2bf(e);
    }
  }
  #pragma unroll
  for (int r = 0; r < 4; ++r) {
    float v = sacc[r];
    v += __shfl_xor(v, 1); v += __shfl_xor(v, 2);
    v += __shfl_xor(v, 4); v += __shfl_xor(v, 8);
    if (l16 == 0) sums[kb * 32 + qb * 16 + quad * 4 + r] = v;
  }
  __syncthreads();
  if (t < 32) invl[t] = 1.0f / (sums[t] + sums[32 + t] + sums[64 + t] + sums[96 + t]);
  __syncthreads();

  // ---- phase 2a: normalized attn weights, fp32, coalesced NT stores ----
  const size_t attn_base = ((size_t)bh * Ss + (size_t)qt * 32) * Ss;
  for (int i = 0; i < 32; ++i) {
    float il = invl[i];
    const unsigned short* pr = P + i * PLD + t * 4;
    floatx4 o;
    o.x = bf2f(pr[0]) * il; o.y = bf2f(pr[1]) * il;
    o.z = bf2f(pr[2]) * il; o.w = bf2f(pr[3]) * il;
    __builtin_nontemporal_store(o, (floatx4*)(attn + attn_base + (size_t)i * Ss + t * 4));
  }

  // ---- phase 2b: O = P @ V (per wave: one 16x16 tile of [32 x 64]) ----
  const int db = kb;
  floatx4 oacc = {0.f, 0.f, 0.f, 0.f};
  const unsigned short* vb = Vt + ((size_t)bh * DK + db * 16 + l16) * Ss + quad * 8;
  const unsigned short* pb = P + (qb * 16 + l16) * PLD + quad * 8;
  #pragma unroll 4
  for (int kk = 0; kk < 64; ++kk) {
    short8 a = *(const short8*)(pb + kk * 32);
    short8 b = *(const short8*)(vb + kk * 32);
    oacc = __builtin_amdgcn_mfma_f32_16x16x32_bf16(a, b, oacc, 0, 0, 0);
  }
  const int bi = bh >> 4, hi = bh & 15;
  #pragma unroll
  for (int r = 0; r < 4; ++r) {
    int ql = qb * 16 + quad * 4 + r;
    int srow = qt * 32 + ql;
    float val = oacc[r] * invl[ql];
    AO[((size_t)(bi * Ss + srow)) * Dm + hi * DK + db * 16 + l16] = f2bf(val);
  }
}

// ---------------------------------------------------------------------------
// Output GEMM: out = AO(bf16) @ Wo^T + bo, fp32 out [8192,1024]
// ---------------------------------------------------------------------------
__global__ __launch_bounds__(256, 2) void out_gemm(
    const unsigned short* __restrict__ AO, const float* __restrict__ W,
    const float* __restrict__ bias, float* __restrict__ out)
{
  __shared__ unsigned short As[BM][LDT];
  __shared__ unsigned short Ws[BN][LDT];

  const int t = threadIdx.x;
  const int lane = t & 63;
  const int w = t >> 6;
  const int wm = w & 1, wn = w >> 1;
  const int quad = lane >> 4, l16 = lane & 15;
  const int mtile = blockIdx.x, ntile = blockIdx.y;

  floatx4 acc[4][4] = {};

  for (int kt = 0; kt < Dm / BK; ++kt) {
    __syncthreads();
    #pragma unroll
    for (int j = 0; j < 4; ++j) {         // A: bf16, 16B chunks
      int c = j * 256 + t;                // 0..1023
      int row = c >> 3, col8 = c & 7;
      short8 v = *(const short8*)(AO + (size_t)(mtile * BM + row) * Dm + kt * BK + col8 * 8);
      *(short8*)&As[row][col8 * 8] = v;
    }
    #pragma unroll
    for (int j = 0; j < 8; ++j) {         // W: fp32 -> bf16
      int c = j * 256 + t;
      int row = c >> 4, col4 = c & 15;
      float4 vw = *(const float4*)(W + (size_t)(ntile * BN + row) * Dm + kt * BK + col4 * 4);
      unsigned short* pw = &Ws[row][col4 * 4];
      pw[0] = f2bf(vw.x); pw[1] = f2bf(vw.y); pw[2] = f2bf(vw.z); pw[3] = f2bf(vw.w);
    }
    __syncthreads();
    #pragma unroll
    for (int kk = 0; kk < 2; ++kk) {
      short8 af[4], bf[4];
      #pragma unroll
      for (int i = 0; i < 4; ++i) {
        af[i] = *(const short8*)&As[wm * 64 + i * 16 + l16][kk * 32 + quad * 8];
        bf[i] = *(const short8*)&Ws[wn * 64 + i * 16 + l16][kk * 32 + quad * 8];
      }
      #pragma unroll
      for (int i = 0; i < 4; ++i)
        #pragma unroll
        for (int jn = 0; jn < 4; ++jn)
          acc[i][jn] = __builtin_amdgcn_mfma_f32_16x16x32_bf16(af[i], bf[jn], acc[i][jn], 0, 0, 0);
    }
  }

  #pragma unroll
  for (int i = 0; i < 4; ++i) {
    int m0 = mtile * BM + wm * 64 + i * 16 + quad * 4;
    #pragma unroll
    for (int jn = 0; jn < 4; ++jn) {
      int n = ntile * BN + wn * 64 + jn * 16 + l16;
      float bv_ = bias[n];
      #pragma unroll
      for (int r = 0; r < 4; ++r)
        out[(size_t)(m0 + r) * Dm + n] = acc[i][jn][r] + bv_;
    }
  }
}

// ---------------------------------------------------------------------------
extern "C" void kernel_launch(void* const* d_in, const int* in_sizes, int n_in,
                              void* d_out, int out_size, void* d_ws, size_t ws_size,
                              hipStream_t stream) {
  const float* query = (const float*)d_in[0];
  const float* key   = (const float*)d_in[1];
  const float* value = (const float*)d_in[2];
  const float* Wq = (const float*)d_in[3];
  const float* bq = (const float*)d_in[4];
  const float* Wk = (const float*)d_in[5];
  const float* bk = (const float*)d_in[6];
  const float* Wv = (const float*)d_in[7];
  const float* bv = (const float*)d_in[8];
  const float* Wo = (const float*)d_in[9];
  const float* bo = (const float*)d_in[10];

  float* out  = (float*)d_out;
  float* attn = out + (size_t)Bb * Ss * Dm;   // attn_weights after output

  const size_t NE = (size_t)Bb * Hh * Ss * DK;  // 8,388,608 elems per tensor
  unsigned short* Qh = (unsigned short*)d_ws;
  unsigned short* Kh = Qh + NE;
  unsigned short* Vt = Kh + NE;
  unsigned short* AO = Vt + NE;

  proj_gemm<<<dim3(Mm / BM, Dm / BN, 3), 256, 0, stream>>>(
      query, key, value, Wq, Wk, Wv, bq, bk, bv, Qh, Kh, Vt);

  const int SMEM = 32 * PLD * 2 + 4 * 32 * 4 + 32 * 4;  // 132,224 B
  hipFuncSetAttribute((const void*)attn_kernel,
                      hipFuncAttributeMaxDynamicSharedMemorySize, SMEM);
  attn_kernel<<<dim3(Ss / 32, Bb * Hh), 512, SMEM, stream>>>(Qh, Kh, Vt, AO, attn);

  out_gemm<<<dim3(Mm / BM, Dm / BN), 256, 0, stream>>>(AO, Wo, bo, out);
}